// Round 11
// baseline (205.040 us; speedup 1.0000x reference)
//
#include <hip/hip_runtime.h>

#define BB 4
#define NN 32768
#define KKN 16          // neighbors per node
#define IN_DIM 32
#define HID 64
#define OUT_DIM 32
#define KH 64
#define WS 72           // LDS row stride in f16 elems (144 B; reads 2-way=free)
#define TOT (BB * NN)   // 131072 = 2^17
#define NWAVES 4096     // grid 1024 blocks x 4 waves

typedef _Float16 f16;
typedef f16 f16x2 __attribute__((ext_vector_type(2)));
typedef f16 f16x4 __attribute__((ext_vector_type(4)));
typedef f16 f16x8 __attribute__((ext_vector_type(8)));
typedef float f32x4 __attribute__((ext_vector_type(4)));
typedef __fp16 hf16x2 __attribute__((ext_vector_type(2)));   // builtin's native type
typedef unsigned int u32x4 __attribute__((ext_vector_type(4)));

#define H2(c) ((f16x2){(f16)(c), (f16)(c)})
#define U2(c) (__builtin_bit_cast(unsigned, H2(c)))

// packed f32->f16x2 convert (v_cvt_pkrtz_f16_f32) -> raw u32 of 2 f16
__device__ __forceinline__ unsigned cvt2u(float a, float b) {
    hf16x2 r = __builtin_amdgcn_cvt_pkrtz(a, b);
    return __builtin_bit_cast(unsigned, r);
}
__device__ __forceinline__ f16x2 cvt2(float a, float b) {
    hf16x2 r = __builtin_amdgcn_cvt_pkrtz(a, b);
    return __builtin_bit_cast(f16x2, r);
}

// ---- single-instruction packed-f16 ops (VOP3P) ----
__device__ __forceinline__ unsigned pk_fma(unsigned a, unsigned b, unsigned c) {
    unsigned d;
    asm("v_pk_fma_f16 %0, %1, %2, %3" : "=v"(d) : "v"(a), "v"(b), "v"(c));
    return d;
}
__device__ __forceinline__ unsigned pk_mul(unsigned a, unsigned b) {
    unsigned d;
    asm("v_pk_mul_f16 %0, %1, %2" : "=v"(d) : "v"(a), "v"(b));
    return d;
}
__device__ __forceinline__ unsigned pk_add(unsigned a, unsigned b) {
    unsigned d;
    asm("v_pk_add_f16 %0, %1, %2" : "=v"(d) : "v"(a), "v"(b));
    return d;
}
__device__ __forceinline__ unsigned pk_max(unsigned a, unsigned b) {
    unsigned d;
    asm("v_pk_max_f16 %0, %1, %2" : "=v"(d) : "v"(a), "v"(b));
    return d;
}
__device__ __forceinline__ unsigned pk_min(unsigned a, unsigned b) {
    unsigned d;
    asm("v_pk_min_f16 %0, %1, %2" : "=v"(d) : "v"(a), "v"(b));
    return d;
}

struct GeluK {
    unsigned n35, p35, q4, c5, c4, c3, c2, c1, c0, half;
};
__device__ __forceinline__ GeluK gelu_consts() {
    GeluK k;
    k.n35  = U2(-3.5f);        k.p35 = U2(3.5f);
    k.q4   = U2(0.25f);        k.half = U2(0.5f);
    k.c5   = U2(-1.0110344f);  k.c4 = U2(2.85016064f);
    k.c3   = U2(-3.40439040f); k.c2 = U2(2.32402432f);
    k.c1   = U2(-1.04974080f); k.c0 = U2(0.39879504f);
    return k;
}

// packed-f16 polynomial gelu on 2 values in one u32.
__device__ __forceinline__ unsigned gelu2u(unsigned x, const GeluK& k) {
    unsigned s  = pk_min(pk_max(x, k.n35), k.p35);
    unsigned s4 = pk_mul(s, k.q4);
    unsigned t  = pk_mul(s4, s4);
    unsigned g  = pk_fma(k.c5, t, k.c4);
    g = pk_fma(g, t, k.c3);
    g = pk_fma(g, t, k.c2);
    g = pk_fma(g, t, k.c1);
    g = pk_fma(g, t, k.c0);
    unsigned h  = pk_fma(s, g, k.half);
    return pk_mul(x, h);
}
__device__ __forceinline__ unsigned gelu2bu(float a, float b, unsigned bias, const GeluK& k) {
    return gelu2u(pk_add(cvt2u(a, b), bias), k);
}

// DPP add: v += lane-permuted v (within 16-lane row).
template <int CTRL>
__device__ __forceinline__ float dppadd(float v) {
    union { float f; int i; } u, r;
    u.f = v;
    r.i = __builtin_amdgcn_update_dpp(0, u.i, CTRL, 0xf, 0xf, true);
    return v + r.f;
}
__device__ __forceinline__ float rowsum16(float v) {
    v = dppadd<0xB1>(v);    // quad xor 1
    v = dppadd<0x4E>(v);    // quad xor 2
    v = dppadd<0x124>(v);   // row rotate 4
    v = dppadd<0x128>(v);   // row rotate 8
    return v;
}

// ---------------- Kernel A: point MLP via MFMA (persistent) ----------------
__global__ __launch_bounds__(256) void point_mlp_kernel(
    const float* __restrict__ inp, const float* __restrict__ Wp1,
    const float* __restrict__ bp1, const float* __restrict__ Wp2,
    const float* __restrict__ bp2, f16* __restrict__ xhf)
{
    __shared__ __align__(16) f16 hb[4][16 * WS];
    const int tid = threadIdx.x, w = tid >> 6, lane = tid & 63;
    const int q = lane >> 4, nl = lane & 15;
    const GeluK gk = gelu_consts();

    f16x8 w1f[4];
    #pragma unroll
    for (int nb = 0; nb < 4; nb++)
        #pragma unroll
        for (int j = 0; j < 8; j++)
            w1f[nb][j] = (f16)Wp1[(q * 8 + j) * HID + nb * 16 + nl];
    f16x8 w2f[2][2];        // rows pre-permuted by p_inv(k) = (k&3)*16 + k/4
    #pragma unroll
    for (int nb = 0; nb < 2; nb++)
        #pragma unroll
        for (int c = 0; c < 2; c++)
            #pragma unroll
            for (int j = 0; j < 8; j++) {
                int k = c * 32 + q * 8 + j, kp = ((k & 3) << 4) | (k >> 2);
                w2f[nb][c][j] = (f16)Wp2[kp * OUT_DIM + nb * 16 + nl];
            }
    const unsigned b1q0 = cvt2u(bp1[nl],      bp1[16 + nl]);
    const unsigned b1q1 = cvt2u(bp1[32 + nl], bp1[48 + nl]);
    float b2v[2];
    b2v[0] = bp2[nl]; b2v[1] = bp2[16 + nl];
    const f32x4 zq = (f32x4){0.f, 0.f, 0.f, 0.f};

    const int gw = blockIdx.x * 4 + w;
    const int nw = gridDim.x * 4;

    for (int t = gw; t < TOT / 16; t += nw) {
        const int R = t * 16;
        const float* ap = inp + (size_t)(R + nl) * IN_DIM + q * 8;
        float4 av0 = *(const float4*)ap, av1 = *(const float4*)(ap + 4);
        f16x2 p01 = cvt2(av0.x, av0.y);
        f16x2 p23 = cvt2(av0.z, av0.w);
        f16x2 p45 = cvt2(av1.x, av1.y);
        f16x2 p67 = cvt2(av1.z, av1.w);
        f16x8 af = (f16x8){p01.x, p01.y, p23.x, p23.y, p45.x, p45.y, p67.x, p67.y};

        f32x4 acc[4];
        #pragma unroll
        for (int nb = 0; nb < 4; nb++)
            acc[nb] = __builtin_amdgcn_mfma_f32_16x16x32_f16(af, w1f[nb], zq, 0, 0, 0);

        #pragma unroll
        for (int r = 0; r < 4; r++) {
            unsigned h01 = gelu2bu(acc[0][r], acc[1][r], b1q0, gk);
            unsigned h23 = gelu2bu(acc[2][r], acc[3][r], b1q1, gk);
            *(uint2*)&hb[w][(q * 4 + r) * WS + nl * 4] = (uint2){h01, h23};
        }
        f16x8 a0 = *(const f16x8*)&hb[w][nl * WS + q * 8];
        f16x8 a1 = *(const f16x8*)&hb[w][nl * WS + 32 + q * 8];
        f32x4 a2[2];
        #pragma unroll
        for (int nb = 0; nb < 2; nb++) {
            a2[nb] = (f32x4){b2v[nb], b2v[nb], b2v[nb], b2v[nb]};
            a2[nb] = __builtin_amdgcn_mfma_f32_16x16x32_f16(a0, w2f[nb][0], a2[nb], 0, 0, 0);
            a2[nb] = __builtin_amdgcn_mfma_f32_16x16x32_f16(a1, w2f[nb][1], a2[nb], 0, 0, 0);
        }
        #pragma unroll
        for (int r = 0; r < 4; r++)
            #pragma unroll
            for (int nb = 0; nb < 2; nb++)
                xhf[(size_t)(R + q * 4 + r) * OUT_DIM + nb * 16 + nl] = (f16)a2[nb][r];
    }
}

// ---------------- Kernel B: edge MLP, 1 node/iter, weights in LDS ----------------
// R11: single-node iteration. R10's counters implied ~2600 VALU/iter at 2
// waves/SIMD -- ~4x the static pk-asm count. Leading suspect: accumulator
// banking into AGPRs (unified file) forcing v_accvgpr_read/write shuffles
// around every MFMA->gelu handoff. Halving live state (acc 32->16 f32,
// prefetch 14->7 regs, 1 LDS tile/wave) fits everything in the arch-VGPR
// bank under the (256,3) cap -> moves vanish, and occupancy has headroom.
// Cost: weight ds_reads no longer amortize over 2 nodes (LDS pipe ~16%, ok).
// Tripwires: WRITE_SIZE must stay 16384; edge >=122us rejects the structure.
__global__ __launch_bounds__(256, 3) void gnn_edge_kernel(
    const f16*   __restrict__ xhf,
    const float* __restrict__ igrid, const float* __restrict__ ogrid,
    const int*   __restrict__ nbi,
    const float* __restrict__ Wk1, const float* __restrict__ bk1,
    const float* __restrict__ Wk2, const float* __restrict__ bk2,
    const float* __restrict__ Wk3, const float* __restrict__ bk3,
    const float* __restrict__ gma, const float* __restrict__ bta,
    float* __restrict__ out)
{
    __shared__ __align__(16) f16 tile[4][16 * WS];   // 1 h-tile/wave, 9.2 KB
    __shared__ __align__(16) f16 wf[20][64][8];      // 20 B-frags, 20.5 KB

    const int tid = threadIdx.x, w = tid >> 6, lane = tid & 63;
    const int q = lane >> 4, nl = lane & 15;
    f16* __restrict__ T = tile[w];
    const GeluK gk = gelu_consts();

    // ---- build weight-frag table: wave w owns frags 5w..5w+4; each lane
    // writes its own 16 B (frag data depends only on lane) ----
    #pragma unroll 1
    for (int f = w * 5; f < w * 5 + 5; ++f) {
        f16x8 v;
        if (f < 4) {                     // w1[nb][0]
            int nb = f;
            #pragma unroll
            for (int j = 0; j < 8; j++)
                v[j] = (f16)Wk1[(4 + q * 8 + j) * KH + nb * 16 + nl];
        } else if (f < 8) {              // w1[nb][1] (pos rows; q==0, j<4 only)
            int nb = f - 4;
            #pragma unroll
            for (int j = 0; j < 8; j++) {
                float x = 0.0f;
                if (j < 4 && q == 0) x = Wk1[j * KH + nb * 16 + nl];
                v[j] = (f16)x;
            }
        } else if (f < 16) {             // w2[nb][c], c = (f-8)/4
            int nb = (f - 8) & 3, c = (f - 8) >> 2;
            #pragma unroll
            for (int j = 0; j < 8; j++) {
                int k = c * 32 + q * 8 + j, kp = ((k & 3) << 4) | (k >> 2);
                v[j] = (f16)Wk2[kp * KH + nb * 16 + nl];
            }
        } else {                         // w3[nb][c] pre-scaled by 1/16
            int nb = (f - 16) & 1, c = (f - 16) >> 1;
            #pragma unroll
            for (int j = 0; j < 8; j++) {
                int k = c * 32 + q * 8 + j, kp = ((k & 3) << 4) | (k >> 2);
                v[j] = (f16)(Wk3[kp * OUT_DIM + nb * 16 + nl] * 0.0625f);
            }
        }
        *(f16x8*)&wf[f][lane][0] = v;
    }
    __syncthreads();   // one-time: weight table ready
    #define WFRAG(f) (*(const f16x8*)&wf[(f)][lane][0])

    // packed-f16 bias pairs for gelu re-injection
    const unsigned b1q0 = cvt2u(bk1[nl],      bk1[16 + nl]);
    const unsigned b1q1 = cvt2u(bk1[32 + nl], bk1[48 + nl]);
    const unsigned b2q0 = cvt2u(bk2[nl],      bk2[16 + nl]);
    const unsigned b2q1 = cvt2u(bk2[32 + nl], bk2[48 + nl]);
    float b3v[2];
    b3v[0] = bk3[nl]; b3v[1] = bk3[16 + nl];
    const float g0 = gma[nl], g1 = gma[16 + nl], be0 = bta[nl], be1 = bta[16 + nl];

    const f32x4 zq = (f32x4){0.f, 0.f, 0.f, 0.f};

    const int gw = blockIdx.x * 4 + w;

    // ---- prologue prefetch (node 0): gather lanes in A-frag order ----
    // lane (q,nl): neighbor row = nbi[node*16 + nl], bytes q*16..q*16+15
    int t = gw;
    int n = nbi[(t & (NN - 1)) * KKN + nl];
    uint4 fy = ((const uint4*)(xhf + ((size_t)((t >> 15) * NN + n)) * OUT_DIM))[q];
    uint2 pa;
    if (q == 0) {
        float2 ip, op;
        ip = ((const float2*)igrid)[n]; op = ((const float2*)ogrid)[t & (NN - 1)];
        pa.x = cvt2u(ip.x, ip.y); pa.y = cvt2u(op.x, op.y);
    }
    f16 x0 = xhf[(size_t)t * OUT_DIM + nl], x1 = xhf[(size_t)t * OUT_DIM + 16 + nl];

    #pragma unroll 1
    for (int it = 0; it < TOT / NWAVES; ++it) {   // 32 iterations
        const float r0 = (float)x0, r1 = (float)x1;

        const int t2 = (t + NWAVES) & (TOT - 1);
        const int n2 = nbi[(t2 & (NN - 1)) * KKN + nl];

        // ---- layer 1: A-operands straight from prefetched registers ----
        f16x8 a0 = __builtin_bit_cast(f16x8, fy);
        u32x4 u1 = (u32x4){q == 0 ? pa.x : 0u, q == 0 ? pa.y : 0u, 0u, 0u};
        f16x8 a1 = __builtin_bit_cast(f16x8, u1);

        f32x4 c[4];
        #pragma unroll
        for (int nb = 0; nb < 4; nb++) {
            f16x8 W0 = WFRAG(nb);
            c[nb] = __builtin_amdgcn_mfma_f32_16x16x32_f16(a0, W0, zq, 0, 0, 0);
        }
        #pragma unroll
        for (int nb = 0; nb < 4; nb++) {
            f16x8 W1 = WFRAG(4 + nb);
            c[nb] = __builtin_amdgcn_mfma_f32_16x16x32_f16(a1, W1, c[nb], 0, 0, 0);
        }
        #pragma unroll
        for (int r = 0; r < 4; r++) {
            unsigned h01 = gelu2bu(c[0][r], c[1][r], b1q0, gk);
            unsigned h23 = gelu2bu(c[2][r], c[3][r], b1q1, gk);
            *(uint2*)&T[(q * 4 + r) * WS + nl * 4] = (uint2){h01, h23};
        }

        // ---- issue next node's gathers (overlap layers 2-3) ----
        uint4 fy2 = ((const uint4*)(xhf + ((size_t)((t2 >> 15) * NN + n2)) * OUT_DIM))[q];
        uint2 pa2;
        if (q == 0) {
            float2 ip, op;
            ip = ((const float2*)igrid)[n2]; op = ((const float2*)ogrid)[t2 & (NN - 1)];
            pa2.x = cvt2u(ip.x, ip.y); pa2.y = cvt2u(op.x, op.y);
        }
        f16 x0n = xhf[(size_t)t2 * OUT_DIM + nl], x1n = xhf[(size_t)t2 * OUT_DIM + 16 + nl];

        // ---- layer 2 ----
        f16x8 b0 = *(const f16x8*)&T[nl * WS + q * 8];
        f16x8 b1 = *(const f16x8*)&T[nl * WS + 32 + q * 8];
        #pragma unroll
        for (int nb = 0; nb < 4; nb++) {
            f16x8 W0 = WFRAG(8 + nb);
            c[nb] = __builtin_amdgcn_mfma_f32_16x16x32_f16(b0, W0, zq, 0, 0, 0);
        }
        #pragma unroll
        for (int nb = 0; nb < 4; nb++) {
            f16x8 W1 = WFRAG(12 + nb);
            c[nb] = __builtin_amdgcn_mfma_f32_16x16x32_f16(b1, W1, c[nb], 0, 0, 0);
        }
        #pragma unroll
        for (int r = 0; r < 4; r++) {
            unsigned h01 = gelu2bu(c[0][r], c[1][r], b2q0, gk);
            unsigned h23 = gelu2bu(c[2][r], c[3][r], b2q1, gk);
            *(uint2*)&T[(q * 4 + r) * WS + nl * 4] = (uint2){h01, h23};
        }

        // ---- layer 3 (w3 pre-scaled by 1/16) ----
        b0 = *(const f16x8*)&T[nl * WS + q * 8];
        b1 = *(const f16x8*)&T[nl * WS + 32 + q * 8];
        f32x4 d[2];
        #pragma unroll
        for (int nb = 0; nb < 2; nb++) {
            f16x8 W0 = WFRAG(16 + nb);
            d[nb] = __builtin_amdgcn_mfma_f32_16x16x32_f16(b0, W0, zq, 0, 0, 0);
        }
        #pragma unroll
        for (int nb = 0; nb < 2; nb++) {
            f16x8 W1 = WFRAG(18 + nb);
            d[nb] = __builtin_amdgcn_mfma_f32_16x16x32_f16(b1, W1, d[nb], 0, 0, 0);
        }

        // ---- epilogue: edge-mean (pre-scaled) + bias + residual, LN over 32 ----
        {
            float s0 = d[0][0] + d[0][1] + d[0][2] + d[0][3];
            float s1 = d[1][0] + d[1][1] + d[1][2] + d[1][3];
            s0 += __shfl_xor(s0, 16, 64); s0 += __shfl_xor(s0, 32, 64);
            s1 += __shfl_xor(s1, 16, 64); s1 += __shfl_xor(s1, 32, 64);

            float o0 = s0 + b3v[0] + r0;
            float o1 = s1 + b3v[1] + r1;

            float m  = rowsum16(o0 + o1) * (1.0f / 32.0f);
            float d0 = o0 - m, d1 = o1 - m;
            float v  = rowsum16(d0 * d0 + d1 * d1) * (1.0f / 32.0f);
            float rs = rsqrtf(v + 1e-5f);

            if (q == 0) {
                float* oa = out + (size_t)t * OUT_DIM;
                oa[nl]      = fmaf(d0 * rs, g0, be0);
                oa[16 + nl] = fmaf(d1 * rs, g1, be1);
            }
        }

        // ---- rotate prefetch state ----
        t = t2;
        fy = fy2; pa = pa2;
        x0 = x0n; x1 = x1n;
    }
    #undef WFRAG
}

extern "C" void kernel_launch(void* const* d_in, const int* in_sizes, int n_in,
                              void* d_out, int out_size, void* d_ws, size_t ws_size,
                              hipStream_t stream) {
    const float* inp   = (const float*)d_in[0];
    const float* igrid = (const float*)d_in[1];
    const float* ogrid = (const float*)d_in[2];
    const int*   nbi   = (const int*)d_in[3];
    const float* Wp1   = (const float*)d_in[4];
    const float* bp1   = (const float*)d_in[5];
    const float* Wp2   = (const float*)d_in[6];
    const float* bp2   = (const float*)d_in[7];
    const float* Wk1   = (const float*)d_in[8];
    const float* bk1   = (const float*)d_in[9];
    const float* Wk2   = (const float*)d_in[10];
    const float* bk2   = (const float*)d_in[11];
    const float* Wk3   = (const float*)d_in[12];
    const float* bk3   = (const float*)d_in[13];
    const float* gma   = (const float*)d_in[14];
    const float* bta   = (const float*)d_in[15];
    float* out = (float*)d_out;
    f16* xhf = (f16*)d_ws;   // B*N*32 f16 = 8 MB

    point_mlp_kernel<<<1024, 256, 0, stream>>>(inp, Wp1, bp1, Wp2, bp2, xhf);
    gnn_edge_kernel<<<1024, 256, 0, stream>>>(xhf, igrid, ogrid, nbi,
                                              Wk1, bk1, Wk2, bk2, Wk3, bk3,
                                              gma, bta, out);
}